// Round 2
// baseline (534.778 us; speedup 1.0000x reference)
//
#include <hip/hip_runtime.h>
#include <math.h>

#define D_MODEL 256
#define N_PATCH 196
#define NWAVES  4        // block = 256 threads
#define N_TILES 2048     // 32 * 64 (b,n) tiles — problem shape is fixed

// One block per (b,n) tile. Single pass over h_p (411 MB read once),
// flash-style online softmax per wave, register-resident accumulator.
__global__ __launch_bounds__(256, 4) void qba_kernel(
    const float* __restrict__ h_p,     // [2048, 196, 256]
    const float* __restrict__ query,   // [256]
    const float* __restrict__ pe,      // [196, 256]
    float* __restrict__ out)           // [2048, 256]
{
    const int t    = threadIdx.x;
    const int lane = t & 63;
    const int w    = t >> 6;
    const int bn   = blockIdx.x;

    // lane l holds q[4l..4l+3]
    const float4 q4 = ((const float4*)query)[lane];

    const float4* hp4 = (const float4*)(h_p + (size_t)bn * N_PATCH * D_MODEL);
    const float4* pe4 = (const float4*)pe;

    float  m = -INFINITY;
    float  l = 0.0f;
    float4 o = {0.0f, 0.0f, 0.0f, 0.0f};

    // wave w handles patches w, w+4, ..., (49 patches each)
    #pragma unroll 2
    for (int p = w; p < N_PATCH; p += NWAVES) {
        const int idx = p * (D_MODEL / 4) + lane;
        float4 h = hp4[idx];
        float4 e = pe4[idx];
        float4 v;
        v.x = h.x + e.x; v.y = h.y + e.y; v.z = h.z + e.z; v.w = h.w + e.w;

        // per-lane partial dot with q, then 64-lane butterfly reduce
        float d = v.x * q4.x + v.y * q4.y + v.z * q4.z + v.w * q4.w;
        #pragma unroll
        for (int off = 32; off > 0; off >>= 1)
            d += __shfl_xor(d, off, 64);

        const float s = d * 0.0625f;   // / sqrt(256)

        // online softmax update (all lanes redundantly; o is per-lane dims)
        const float m_new = fmaxf(m, s);
        const float alpha = __expf(m - m_new);  // exp(-inf)=0 on first iter
        const float wp    = __expf(s - m_new);
        l   = l * alpha + wp;
        o.x = o.x * alpha + wp * v.x;
        o.y = o.y * alpha + wp * v.y;
        o.z = o.z * alpha + wp * v.z;
        o.w = o.w * alpha + wp * v.w;
        m = m_new;
    }

    // merge the 4 per-wave states
    __shared__ float sm[NWAVES];
    __shared__ float sl[NWAVES];
    __shared__ float so[NWAVES][D_MODEL];

    if (lane == 0) { sm[w] = m; sl[w] = l; }
    *((float4*)&so[w][lane * 4]) = o;
    __syncthreads();

    const float M  = fmaxf(fmaxf(sm[0], sm[1]), fmaxf(sm[2], sm[3]));
    const float e0 = __expf(sm[0] - M);
    const float e1 = __expf(sm[1] - M);
    const float e2 = __expf(sm[2] - M);
    const float e3 = __expf(sm[3] - M);
    const float L  = sl[0] * e0 + sl[1] * e1 + sl[2] * e2 + sl[3] * e3;

    // thread t owns output dim t; so[w][t] reads are stride-1 across threads
    const float num = so[0][t] * e0 + so[1][t] * e1 + so[2][t] * e2 + so[3][t] * e3;
    out[(size_t)bn * D_MODEL + t] = num / L;
}

extern "C" void kernel_launch(void* const* d_in, const int* in_sizes, int n_in,
                              void* d_out, int out_size, void* d_ws, size_t ws_size,
                              hipStream_t stream) {
    (void)in_sizes; (void)n_in; (void)d_ws; (void)ws_size; (void)out_size;
    const float* h_p   = (const float*)d_in[0];  // [32,64,196,256]
    const float* query = (const float*)d_in[1];  // [1,1,256]
    const float* pe    = (const float*)d_in[2];  // [1,196,256]
    float* out = (float*)d_out;                  // [32,64,256]

    // Problem shape is fixed; take nothing from host-side size arrays so the
    // captured graph and every fresh launch do identical work.
    qba_kernel<<<N_TILES, 256, 0, stream>>>(h_p, query, pe, out);
}

// Round 3
// 529.456 us; speedup vs baseline: 1.0101x; 1.0101x over previous
//
#include <hip/hip_runtime.h>
#include <math.h>

#define D_MODEL 256
#define N_PATCH 196
#define NWAVES  4        // block = 256 threads
#define N_TILES 2048     // 32 * 64 (b,n) tiles — problem shape is fixed

// One block per (b,n) tile. Single pass over h_p (411 MB read once).
// Wave w owns patches p = w + 4k, k in [0,49). Main loop: 4 patches per
// iteration (12 iters) for MLP + pipelined shuffle reduces; 1 tail patch.
__global__ __launch_bounds__(256, 4) void qba_kernel(
    const float* __restrict__ h_p,     // [2048, 196, 256]
    const float* __restrict__ query,   // [256]
    const float* __restrict__ pe,      // [196, 256]
    float* __restrict__ out)           // [2048, 256]
{
    const int t    = threadIdx.x;
    const int lane = t & 63;
    const int w    = t >> 6;
    const int bn   = blockIdx.x;

    // lane l holds q[4l..4l+3]
    const float4 q4 = ((const float4*)query)[lane];

    const float4* hp4 = (const float4*)(h_p + (size_t)bn * N_PATCH * D_MODEL);
    const float4* pe4 = (const float4*)pe;

    float  m = -INFINITY;
    float  l = 0.0f;
    float4 o = {0.0f, 0.0f, 0.0f, 0.0f};

    // ---- main loop: 12 iterations x 4 patches ----
    for (int i = 0; i < 12; ++i) {
        // patch j: p_j = w + 16*i + 4*j   (j = 0..3), all < 192
        const int base = (w + 16 * i) * (D_MODEL / 4) + lane;
        const int i0 = base;
        const int i1 = base + 4 * (D_MODEL / 4);
        const int i2 = base + 8 * (D_MODEL / 4);
        const int i3 = base + 12 * (D_MODEL / 4);

        // issue all 8 loads before any use (4 KB/wave in flight)
        float4 h0 = hp4[i0]; float4 h1 = hp4[i1];
        float4 h2 = hp4[i2]; float4 h3 = hp4[i3];
        float4 e0 = pe4[i0]; float4 e1 = pe4[i1];
        float4 e2 = pe4[i2]; float4 e3 = pe4[i3];

        float4 v0, v1, v2, v3;
        v0.x = h0.x + e0.x; v0.y = h0.y + e0.y; v0.z = h0.z + e0.z; v0.w = h0.w + e0.w;
        v1.x = h1.x + e1.x; v1.y = h1.y + e1.y; v1.z = h1.z + e1.z; v1.w = h1.w + e1.w;
        v2.x = h2.x + e2.x; v2.y = h2.y + e2.y; v2.z = h2.z + e2.z; v2.w = h2.w + e2.w;
        v3.x = h3.x + e3.x; v3.y = h3.y + e3.y; v3.z = h3.z + e3.z; v3.w = h3.w + e3.w;

        float d0 = v0.x * q4.x + v0.y * q4.y + v0.z * q4.z + v0.w * q4.w;
        float d1 = v1.x * q4.x + v1.y * q4.y + v1.z * q4.z + v1.w * q4.w;
        float d2 = v2.x * q4.x + v2.y * q4.y + v2.z * q4.z + v2.w * q4.w;
        float d3 = v3.x * q4.x + v3.y * q4.y + v3.z * q4.z + v3.w * q4.w;

        // 4 independent butterflies — DS ops pipeline across the 4 chains
        #pragma unroll
        for (int off = 32; off > 0; off >>= 1) {
            d0 += __shfl_xor(d0, off, 64);
            d1 += __shfl_xor(d1, off, 64);
            d2 += __shfl_xor(d2, off, 64);
            d3 += __shfl_xor(d3, off, 64);
        }

        const float s0 = d0 * 0.0625f;
        const float s1 = d1 * 0.0625f;
        const float s2 = d2 * 0.0625f;
        const float s3 = d3 * 0.0625f;

        // batched online-softmax update (one rescale for 4 patches)
        const float m_new = fmaxf(fmaxf(fmaxf(m, s0), fmaxf(s1, s2)), s3);
        const float alpha = __expf(m - m_new);      // exp(-inf)=0 on first iter
        const float w0 = __expf(s0 - m_new);
        const float w1 = __expf(s1 - m_new);
        const float w2 = __expf(s2 - m_new);
        const float w3 = __expf(s3 - m_new);
        l = l * alpha + (w0 + w1 + w2 + w3);
        o.x = o.x * alpha + w0 * v0.x + w1 * v1.x + w2 * v2.x + w3 * v3.x;
        o.y = o.y * alpha + w0 * v0.y + w1 * v1.y + w2 * v2.y + w3 * v3.y;
        o.z = o.z * alpha + w0 * v0.z + w1 * v1.z + w2 * v2.z + w3 * v3.z;
        o.w = o.w * alpha + w0 * v0.w + w1 * v1.w + w2 * v2.w + w3 * v3.w;
        m = m_new;
    }

    // ---- tail: k = 48, p = 192 + w (all valid, no guard) ----
    {
        const int idx = (192 + w) * (D_MODEL / 4) + lane;
        float4 h = hp4[idx];
        float4 e = pe4[idx];
        float4 v;
        v.x = h.x + e.x; v.y = h.y + e.y; v.z = h.z + e.z; v.w = h.w + e.w;

        float d = v.x * q4.x + v.y * q4.y + v.z * q4.z + v.w * q4.w;
        #pragma unroll
        for (int off = 32; off > 0; off >>= 1)
            d += __shfl_xor(d, off, 64);

        const float s = d * 0.0625f;
        const float m_new = fmaxf(m, s);
        const float alpha = __expf(m - m_new);
        const float wp    = __expf(s - m_new);
        l   = l * alpha + wp;
        o.x = o.x * alpha + wp * v.x;
        o.y = o.y * alpha + wp * v.y;
        o.z = o.z * alpha + wp * v.z;
        o.w = o.w * alpha + wp * v.w;
        m = m_new;
    }

    // ---- merge the 4 per-wave states ----
    __shared__ float sm[NWAVES];
    __shared__ float sl[NWAVES];
    __shared__ float so[NWAVES][D_MODEL];

    if (lane == 0) { sm[w] = m; sl[w] = l; }
    *((float4*)&so[w][lane * 4]) = o;
    __syncthreads();

    const float M  = fmaxf(fmaxf(sm[0], sm[1]), fmaxf(sm[2], sm[3]));
    const float e0 = __expf(sm[0] - M);
    const float e1 = __expf(sm[1] - M);
    const float e2 = __expf(sm[2] - M);
    const float e3 = __expf(sm[3] - M);
    const float L  = sl[0] * e0 + sl[1] * e1 + sl[2] * e2 + sl[3] * e3;

    const float num = so[0][t] * e0 + so[1][t] * e1 + so[2][t] * e2 + so[3][t] * e3;
    out[(size_t)bn * D_MODEL + t] = num / L;
}

extern "C" void kernel_launch(void* const* d_in, const int* in_sizes, int n_in,
                              void* d_out, int out_size, void* d_ws, size_t ws_size,
                              hipStream_t stream) {
    (void)in_sizes; (void)n_in; (void)d_ws; (void)ws_size; (void)out_size;
    const float* h_p   = (const float*)d_in[0];  // [32,64,196,256]
    const float* query = (const float*)d_in[1];  // [1,1,256]
    const float* pe    = (const float*)d_in[2];  // [1,196,256]
    float* out = (float*)d_out;                  // [32,64,256]

    qba_kernel<<<N_TILES, 256, 0, stream>>>(h_p, query, pe, out);
}